// Round 11
// baseline (99.915 us; speedup 1.0000x reference)
//
#include <hip/hip_runtime.h>

// EdgeEmbedding: B=8, L=256, A=15, K=9, EDGE_SIZE=16.
//
// Output layout (all float32, concatenated flat):
//   [0,      30720)  block_id   = i/15
//   [30720,  32768)  batch_id   = i/256
//   [32768, 106496)  edges [2][36864]   (row0 src, row1 dst; intra then inter)
//   [106496,696320)  edge_attr [36864][16]
//
// Round-11 (rounds 8-10 post-mortem: phase-1 candidate loads had 180 B lane
// stride -> ~64 cache-line requests per wave-load, ~10+ us of unhideable
// TA/L1 serialization; two stall-theories on the selection tail were
// neutral): transpose pos into d_ws once (coalesced SoA [b][a*3+d][l]),
// then phase 1 reads lane-stride-4B fully-coalesced rows.
// Pipeline (math / f64 ordering identical to round-4 oracle-match):
//   1. f32 min-d^2/candidate: {-2x,-2y,-2z,x2} SGPR-pinned row atoms,
//      4 VALU/pair, +c2 hoisted; candidate atoms from transposed T.
//   2. Histogram quantile (512 bins on bits>>19); all waves scan both
//      classes -> thresholds in registers.
//   3. Mark d32 <= T + DELTA (DELTA=5e-3 >= 8x f32 err bound => superset
//      of f64 top-9); dense (cand,cls) + promoted-f32 key.
//   4. Lazy f64 refine only for same-class pairs within EPS2=2e-3 (>3x err;
//      usually zero). Refined = full 225-pair f64 min on ORIGINAL pos
//      (bit-identical to round 4). Mixed-key ranking exact (gap arguments).
//   5. Rank per slot -> winners write ordered edge slots.

#define BB   8
#define LL   256
#define AA   15
#define KK   9

#define O_BATCH   30720
#define O_EDGES   32768
#define NE_HALF   18432   // B*L*K
#define NE        36864
#define O_ATTR    106496
#define DELTA     0.005f
#define EPS2      2e-3
#define HBASE     1904    // (0x3B800000 >> 19): bins start at 2^-8
#define NBIN      512
#define MAXM      128     // marked-list capacity (observed cnt ~18-22)

__device__ __forceinline__ float rfl(float v) {
    return __int_as_float(__builtin_amdgcn_readfirstlane(__float_as_int(v)));
}

// ---------------------------------------------------------------------------
// Kernel T: pos [B,L,A,3] -> T [B, A*3, L]  (360 blocks x 256 threads).
// One scatter-read per thread (amortized 68x vs per-block scatter), write
// coalesced.
// ---------------------------------------------------------------------------
__global__ __launch_bounds__(256) void transpose_kernel(
    const float* __restrict__ pos, float* __restrict__ T)
{
    const int bk = blockIdx.x;               // = b*45 + k, 0..359
    const int bq = bk / 45, k = bk - bq * 45;
    const int l  = threadIdx.x;
    T[bk * LL + l] = pos[((size_t)(bq * LL + l)) * 45 + k];
}

__global__ __launch_bounds__(256) void edge_fused_kernel(
    const float* __restrict__ pos,   // [B,L,A,3] f32 (refine path)
    const float* __restrict__ Tp,    // [B,45,L] transposed (hot path)
    const int*   __restrict__ frag,  // [B,L]
    const float* __restrict__ emb,   // [2,16]
    float*       __restrict__ out)
{
    const int blk = blockIdx.x;      // = b*256 + i
    const int b   = blk >> 8;
    const int i   = blk & 255;
    const int j   = threadIdx.x;     // candidate dst block

    __shared__ float4 sAi4[AA];      // row-i: {-2x, -2y, -2z, |x|^2}
    __shared__ double dAi[AA * 3];   // row-i coords (f64, rare-refine path)
    __shared__ double dX2i[AA];      // row-i |x|^2 (f64)
    __shared__ int    sHist[2*NBIN]; // per-class histogram
    __shared__ int    sList[MAXM];   // (cand<<1)|class, dense
    __shared__ double sVal[MAXM];    // comparison key (d32-promoted or d64)
    __shared__ int    sRList[MAXM];  // slots needing f64 refine
    __shared__ int    sCnt, sRCnt;

    // ---- fused trivial fills ----
    if (j < AA)  out[blk * AA + j]  = (float)blk;     // block_id
    if (j == AA) out[O_BATCH + blk] = (float)b;       // batch_id
    {
        int idx = blk * 288 + j;                      // 288 attr elems/block
        out[O_ATTR + idx] = emb[(((idx >> 4) < NE_HALF) ? 0 : 16) + (idx & 15)];
        if (j < 32) {
            int idx2 = idx + 256;
            out[O_ATTR + idx2] = emb[(((idx2 >> 4) < NE_HALF) ? 0 : 16) + (idx2 & 15)];
        }
    }

    // ---- stage row-i atoms; zero hist; init counters ----
    if (j < AA) {
        const float* p = pos + (size_t)blk * 45 + j * 3;
        float x = p[0], y = p[1], z = p[2];
        sAi4[j] = make_float4(-2.0f * x, -2.0f * y, -2.0f * z,
                              x*x + y*y + z*z);
        double dx = (double)x, dy = (double)y, dz = (double)z;
        dAi[3*j] = dx; dAi[3*j+1] = dy; dAi[3*j+2] = dz;
        dX2i[j] = dx*dx + dy*dy + dz*dz;
    }
    #pragma unroll
    for (int q = 0; q < 4; ++q) sHist[j + (q << 8)] = 0;   // 1024 ints
    if (j == 255) sCnt = 0;
    if (j == 254) sRCnt = 0;

    const int ftj  = frag[b * LL + j];
    const int segj = (ftj == 2) ? 1 : ftj;
    const int fti  = frag[blk];                       // uniform
    const int segi = (fti == 2) ? 1 : fti;
    // class: 0 = intra (seg==segi, j!=i), 1 = inter, -1 = self
    const int cls  = (j == i) ? -1 : ((segj == segi) ? 0 : 1);
    __syncthreads();                                  // bar 1

    // ---- row-i atoms: LDS once -> wave-uniform (SGPR) copies ----
    float Ax[AA], Ay[AA], Az[AA], Aw[AA];
    #pragma unroll
    for (int a = 0; a < AA; ++a) {
        float4 A = sAi4[a];
        Ax[a] = rfl(A.x); Ay[a] = rfl(A.y);
        Az[a] = rfl(A.z); Aw[a] = rfl(A.w);
    }

    // ---- phase 1: f32 min d^2; candidate atoms via coalesced T rows ----
    const float* Tb = Tp + (size_t)b * 45 * LL;
    float d32 = INFINITY;
    #pragma unroll 1
    for (int cb = 0; cb < AA; cb += 5) {
        float cx[5], cy[5], cz[5], c2[5], m[5];
        #pragma unroll
        for (int q = 0; q < 5; ++q) {
            const int at = cb + q;
            cx[q] = Tb[(3*at + 0) * LL + j];          // lane stride 4 B
            cy[q] = Tb[(3*at + 1) * LL + j];
            cz[q] = Tb[(3*at + 2) * LL + j];
            c2[q] = cx[q]*cx[q] + cy[q]*cy[q] + cz[q]*cz[q];
            m[q]  = INFINITY;
        }
        #pragma unroll
        for (int a = 0; a < AA; ++a) {
            #pragma unroll
            for (int q = 0; q < 5; ++q) {
                float dp = fmaf(Ax[a], cx[q], fmaf(Ay[a], cy[q],
                            fmaf(Az[a], cz[q], Aw[a])));
                m[q] = fminf(m[q], dp);
            }
        }
        #pragma unroll
        for (int q = 0; q < 5; ++q)
            d32 = fminf(d32, m[q] + c2[q]);
    }
    d32 = fmaxf(d32, 0.0f);

    // ---- phase 2a: histogram (bits>>19 monotone for d32 >= 0) ----
    if (cls >= 0) {
        int bin = (int)(__float_as_uint(d32) >> 19) - HBASE;
        bin = min(NBIN - 1, max(0, bin));
        atomicAdd(&sHist[cls * NBIN + bin], 1);
    }
    __syncthreads();                                  // bar 2

    // ---- phase 2b: every wave scans BOTH classes (thresholds in regs) ----
    const int lane = j & 63;
    float T[2];
    #pragma unroll
    for (int cw = 0; cw < 2; ++cw) {
        int c[8], s = 0;
        #pragma unroll
        for (int q = 0; q < 8; ++q) {
            c[q] = sHist[cw * NBIN + 8*lane + q];
            s += c[q];
        }
        int cum = s;
        #pragma unroll
        for (int off = 1; off < 64; off <<= 1) {
            int v = __shfl_up(cum, off, 64);
            if (lane >= off) cum += v;
        }
        unsigned long long msk = __ballot(cum >= KK);
        float t_ = INFINITY;
        if (msk != 0ull) {
            int f = __builtin_ctzll(msk);
            if (lane == f) {
                int before = cum - s, bin = -1;
                #pragma unroll
                for (int q = 0; q < 8; ++q) {
                    before += c[q];
                    if (bin < 0 && before >= KK) bin = 8*f + q;
                }
                t_ = (bin >= NBIN - 1) ? INFINITY
                   : __uint_as_float((unsigned)(HBASE + bin + 1) << 19);
            }
            t_ = __shfl(t_, f, 64);                  // broadcast from lane f
        }
        T[cw] = t_;
    }

    // ---- phase 3: mark; store dense (cand,cls) + promoted-f32 key ----
    if (cls >= 0 && d32 <= T[cls] + DELTA) {
        int p = atomicAdd(&sCnt, 1);
        if (p < MAXM) {
            sList[p] = (j << 1) | cls;
            sVal[p]  = (double)d32;
        }
    }
    __syncthreads();                                  // bar 3
    const int cnt = min(sCnt, MAXM);                  // ~18-22

    // ---- phase 4a: near-tie detection (independent broadcast reads) ----
    if (j < cnt) {
        double my = sVal[j];
        int mycls = sList[j] & 1;
        bool need = false;
        for (int u = 0; u < cnt; ++u) {
            if (u != j && (sList[u] & 1) == mycls &&
                fabs(sVal[u] - my) <= EPS2) need = true;
        }
        if (need) { int p = atomicAdd(&sRCnt, 1); sRList[p] = j; }
    }
    __syncthreads();                                  // bar 4

    // ---- phase 4b: rare cooperative f64 refine (usually rcnt == 0) ----
    {
        const int rcnt = sRCnt;
        const int wv = j >> 6;
        for (int base = 0; base < rcnt; base += 4) {
            int t = base + wv;
            double dmin = INFINITY;
            int slot = -1;
            if (t < rcnt) {
                slot = sRList[t];
                int cand = sList[slot] >> 1;
                const float* pc = pos + (size_t)(b * LL + cand) * 45;
                for (int p = lane; p < 225; p += 64) {
                    int a = p / 15, c = p - a * 15;
                    double cx = (double)pc[3*c], cy = (double)pc[3*c+1],
                           cz = (double)pc[3*c+2];
                    double dot = dAi[3*a]*cx + dAi[3*a+1]*cy + dAi[3*a+2]*cz;
                    double d2  = (dX2i[a] + (cx*cx + cy*cy + cz*cz))
                               - 2.0 * dot;
                    dmin = fmin(dmin, d2);
                }
            }
            #pragma unroll
            for (int off = 1; off < 64; off <<= 1)
                dmin = fmin(dmin, __shfl_xor(dmin, off, 64));
            if (lane == 0 && t < rcnt) sVal[slot] = fmax(dmin, 0.0);
        }
    }
    __syncthreads();                                  // bar 5

    // ---- phase 5: rank per slot; winners write ordered edge slots ----
    if (j < cnt) {
        int e   = sList[j];
        int cnd = e >> 1, mycls = e & 1;
        double key = sVal[j];
        int r = 0;
        for (int u = 0; u < cnt; ++u) {
            int eu = sList[u];
            if ((eu & 1) == mycls) {
                double ku = sVal[u];
                int cu = eu >> 1;
                if (ku < key || (ku == key && cu < cnd)) ++r;
            }
        }
        if (r < KK) {
            int eo = (mycls == 0 ? 0 : NE_HALF) + blk * KK + r;
            out[O_EDGES + eo]      = (float)blk;            // src
            out[O_EDGES + NE + eo] = (float)(b * LL + cnd); // dst
        }
    }
}

extern "C" void kernel_launch(void* const* d_in, const int* in_sizes, int n_in,
                              void* d_out, int out_size, void* d_ws, size_t ws_size,
                              hipStream_t stream) {
    const float* pos  = (const float*)d_in[0];   // pos_heavyatom [8,256,15,3] f32
    const int*   frag = (const int*)d_in[6];     // fragment_type [8,256] i32
    const float* emb  = (const float*)d_in[7];   // edge_emb [2,16] f32
    float* out = (float*)d_out;
    float* Tws = (float*)d_ws;                   // 8*45*256 floats = 368.6 KB

    transpose_kernel<<<dim3(BB * 45), dim3(256), 0, stream>>>(pos, Tws);
    edge_fused_kernel<<<dim3(BB * LL), dim3(256), 0, stream>>>(pos, Tws, frag,
                                                               emb, out);
}

// Round 12
// 90.081 us; speedup vs baseline: 1.1092x; 1.1092x over previous
//
#include <hip/hip_runtime.h>

// EdgeEmbedding: B=8, L=256, A=15, K=9, EDGE_SIZE=16 — two kernels + 2MB d_ws.
//
// Output layout (all float32, concatenated flat):
//   [0,      30720)  block_id   = i/15
//   [30720,  32768)  batch_id   = i/256
//   [32768, 106496)  edges [2][36864]   (row0 src, row1 dst; intra then inter)
//   [106496,696320)  edge_attr [36864][16]
//
// Round-12 (rounds 9-11 post-mortem: three stall theories neutral; R7 PMC
// (45us, VALUBusy 60%) says the kernel is ~VALU-issue-bound => cut the
// instruction count. The dominant term is 225 pairs x 4 ops x 524k threads;
// d^2(i,j)=d^2(j,i) symmetry halves it but needs a matrix formulation):
//   K1: triangular 16x16 block-tiles (8 x 136 blocks); thread = one (i,j)
//       block pair; d^2 written to both orders; f32, {-2x,..,x2} packing.
//   K2: per-row selection: read d^2 row (1 coalesced load/thread),
//       128-bin histogram quantile -> threshold T >= v9; mark
//       d <= T + DELTA (DELTA=5e-3 >= 8x f32-err => marked superset of the
//       f64 top-9); lazy f64 refine (same-class pairs within EPS2=2e-3 only;
//       usually zero) on ORIGINAL pos — bit-identical to the round-4 all-f64
//       kernel that matched the oracle (absmax 37); rank -> ordered writes.

#define BB   8
#define LL   256
#define AA   15
#define KK   9

#define O_BATCH   30720
#define O_EDGES   32768
#define NE_HALF   18432   // B*L*K
#define NE        36864
#define O_ATTR    106496
#define DELTA     0.005f
#define EPS2      2e-3
#define HBASE     448     // (0x38000000 >> 21)
#define NBIN      128
#define MAXM      128

#define TW        16      // tile width
#define NTILE     136     // 16*17/2 triangular tiles

// ---------------------------------------------------------------------------
// K1: block-pair distance tiles.  grid = B * 136.
// tile (ti,tj), tj>=ti; thread (il = tid>>4, jl = tid&15) computes
// min-atom-pair d^2 between blocks i=16ti+il and j=16tj+jl, writes both
// D[i][j] and D[j][i].  Diagonal tiles mask jl<il (transpose covers them).
// ---------------------------------------------------------------------------
__global__ __launch_bounds__(256) void dist_kernel(
    const float* __restrict__ pos,   // [B,L,A,3]
    float*       __restrict__ D)     // [B,L,L]
{
    const int bx = blockIdx.x;
    const int b  = bx / NTILE;
    const int t  = bx - b * NTILE;
    // decode triangular index: off(r) = r*(33-r)/2
    int ti = (int)((33.0f - sqrtf(1089.0f - 8.0f * (float)t)) * 0.5f);
    while (ti * (33 - ti) / 2 > t) --ti;
    while ((ti + 1) * (32 - ti) / 2 <= t) ++ti;
    const int tj = ti + (t - ti * (33 - ti) / 2);
    const int I0 = ti * TW, J0 = tj * TW;

    __shared__ float4 sI[AA][TW];    // i-side: {-2x,-2y,-2z,x2}
    __shared__ float4 sJ[AA][TW];    // j-side: { x,  y,  z, x2}

    const int tid = threadIdx.x;
    if (tid < 240) {                 // 240 atoms per side
        const int bl = tid / AA, a = tid - bl * AA;
        {
            const float* p = pos + ((size_t)(b * LL + I0 + bl) * 45) + a * 3;
            float x = p[0], y = p[1], z = p[2];
            sI[a][bl] = make_float4(-2.f*x, -2.f*y, -2.f*z, x*x + y*y + z*z);
        }
        {
            const float* p = pos + ((size_t)(b * LL + J0 + bl) * 45) + a * 3;
            float x = p[0], y = p[1], z = p[2];
            sJ[a][bl] = make_float4(x, y, z, x*x + y*y + z*z);
        }
    }
    __syncthreads();

    const int il = tid >> 4, jl = tid & 15;

    float4 J[AA];
    float  m[AA];
    #pragma unroll
    for (int c = 0; c < AA; ++c) { J[c] = sJ[c][jl]; m[c] = INFINITY; }

    #pragma unroll
    for (int a = 0; a < AA; ++a) {
        float4 A = sI[a][il];        // broadcast across 16 lanes
        #pragma unroll
        for (int c = 0; c < AA; ++c) {
            float dp = fmaf(A.x, J[c].x,
                       fmaf(A.y, J[c].y,
                       fmaf(A.z, J[c].z, A.w)));
            m[c] = fminf(m[c], dp);
        }
    }
    float v = INFINITY;
    #pragma unroll
    for (int c = 0; c < AA; ++c) v = fminf(v, m[c] + J[c].w);
    v = fmaxf(v, 0.0f);

    if (ti != tj || jl >= il) {
        const int i = I0 + il, j = J0 + jl;
        const size_t base = ((size_t)b) << 16;
        D[base + (i << 8) + j] = v;
        D[base + (j << 8) + i] = v;
    }
}

// ---------------------------------------------------------------------------
// K2: per-row selection + fills.  grid = B * L.
// ---------------------------------------------------------------------------
__global__ __launch_bounds__(256) void select_kernel(
    const float* __restrict__ pos,   // [B,L,A,3] (f64 refine path)
    const float* __restrict__ D,     // [B,L,L] f32 min d^2
    const int*   __restrict__ frag,  // [B,L]
    const float* __restrict__ emb,   // [2,16]
    float*       __restrict__ out)
{
    const int blk = blockIdx.x;      // = b*256 + i
    const int b   = blk >> 8;
    const int i   = blk & 255;
    const int j   = threadIdx.x;     // candidate dst block

    __shared__ double dAi[AA * 3];   // row-i coords (f64, refine path)
    __shared__ double dX2i[AA];
    __shared__ int    sHist[2 * NBIN];
    __shared__ int    sList[MAXM];   // (cand<<1)|class
    __shared__ double sVal[MAXM];    // key: promoted f32 or refined f64
    __shared__ int    sRList[MAXM];
    __shared__ int    sCnt, sRCnt;

    // ---- fused trivial fills ----
    if (j < AA)  out[blk * AA + j]  = (float)blk;     // block_id
    if (j == AA) out[O_BATCH + blk] = (float)b;       // batch_id
    {
        int idx = blk * 288 + j;
        out[O_ATTR + idx] = emb[(((idx >> 4) < NE_HALF) ? 0 : 16) + (idx & 15)];
        if (j < 32) {
            int idx2 = idx + 256;
            out[O_ATTR + idx2] = emb[(((idx2 >> 4) < NE_HALF) ? 0 : 16) + (idx2 & 15)];
        }
    }

    // ---- stage row-i atoms in f64 (refine path); zero hist ----
    if (j < AA) {
        const float* p = pos + (size_t)blk * 45 + j * 3;
        double dx = (double)p[0], dy = (double)p[1], dz = (double)p[2];
        dAi[3*j] = dx; dAi[3*j+1] = dy; dAi[3*j+2] = dz;
        dX2i[j] = dx*dx + dy*dy + dz*dz;
    }
    if (j < 2 * NBIN) sHist[j] = 0;
    if (j == 255) sCnt = 0;
    if (j == 254) sRCnt = 0;

    const int ftj  = frag[b * LL + j];
    const int segj = (ftj == 2) ? 1 : ftj;
    const int fti  = frag[blk];
    const int segi = (fti == 2) ? 1 : fti;
    // class: 0 = intra (seg==segi, j!=i), 1 = inter, -1 = self
    const int cls  = (j == i) ? -1 : ((segj == segi) ? 0 : 1);

    // ---- read d^2 from matrix (coalesced) ----
    const float d32 = D[(((size_t)b) << 16) + (i << 8) + j];
    __syncthreads();                                  // hist zero visible

    // ---- histogram (bits>>21 monotone for d32 >= 0) ----
    if (cls >= 0) {
        int bin = (int)(__float_as_uint(d32) >> 21) - HBASE;
        bin = min(NBIN - 1, max(0, bin));
        atomicAdd(&sHist[cls * NBIN + bin], 1);
    }
    __syncthreads();

    // ---- every wave scans both classes (2 bins/lane), T in registers ----
    const int lane = j & 63;
    float T[2];
    #pragma unroll
    for (int cw = 0; cw < 2; ++cw) {
        int c0 = sHist[cw * NBIN + 2*lane];
        int c1 = sHist[cw * NBIN + 2*lane + 1];
        int s  = c0 + c1;
        int cum = s;
        #pragma unroll
        for (int off = 1; off < 64; off <<= 1) {
            int v = __shfl_up(cum, off, 64);
            if (lane >= off) cum += v;
        }
        unsigned long long msk = __ballot(cum >= KK);
        float t_ = INFINITY;
        if (msk != 0ull) {
            int f = __builtin_ctzll(msk);
            if (lane == f) {
                int before = cum - s;
                int bin = (before + c0 >= KK) ? 2*f : 2*f + 1;
                t_ = (bin >= NBIN - 1) ? INFINITY
                   : __uint_as_float((unsigned)(HBASE + bin + 1) << 21);
            }
            t_ = __shfl(t_, f, 64);
        }
        T[cw] = t_;
    }

    // ---- mark superset; dense list + promoted-f32 keys ----
    if (cls >= 0 && d32 <= T[cls] + DELTA) {
        int p = atomicAdd(&sCnt, 1);
        if (p < MAXM) {
            sList[p] = (j << 1) | cls;
            sVal[p]  = (double)d32;
        }
    }
    __syncthreads();
    const int cnt = min(sCnt, MAXM);                  // ~20-28

    // ---- near-tie detection ----
    if (j < cnt) {
        double my = sVal[j];
        int mycls = sList[j] & 1;
        bool need = false;
        for (int u = 0; u < cnt; ++u) {
            if (u != j && (sList[u] & 1) == mycls &&
                fabs(sVal[u] - my) <= EPS2) need = true;
        }
        if (need) { int p = atomicAdd(&sRCnt, 1); sRList[p] = j; }
    }
    __syncthreads();

    // ---- rare cooperative f64 refine (usually rcnt == 0) ----
    {
        const int rcnt = sRCnt;
        const int wv = j >> 6;
        for (int base = 0; base < rcnt; base += 4) {
            int t = base + wv;
            double dmin = INFINITY;
            int slot = -1;
            if (t < rcnt) {
                slot = sRList[t];
                int cand = sList[slot] >> 1;
                const float* pc = pos + (size_t)(b * LL + cand) * 45;
                for (int p = lane; p < 225; p += 64) {
                    int a = p / 15, c = p - a * 15;
                    double cx = (double)pc[3*c], cy = (double)pc[3*c+1],
                           cz = (double)pc[3*c+2];
                    double dot = dAi[3*a]*cx + dAi[3*a+1]*cy + dAi[3*a+2]*cz;
                    double d2  = (dX2i[a] + (cx*cx + cy*cy + cz*cz))
                               - 2.0 * dot;
                    dmin = fmin(dmin, d2);
                }
            }
            #pragma unroll
            for (int off = 1; off < 64; off <<= 1)
                dmin = fmin(dmin, __shfl_xor(dmin, off, 64));
            if (lane == 0 && t < rcnt) sVal[slot] = fmax(dmin, 0.0);
        }
    }
    __syncthreads();

    // ---- rank per slot; winners write ordered edge slots ----
    if (j < cnt) {
        int e   = sList[j];
        int cnd = e >> 1, mycls = e & 1;
        double key = sVal[j];
        int r = 0;
        for (int u = 0; u < cnt; ++u) {
            int eu = sList[u];
            if ((eu & 1) == mycls) {
                double ku = sVal[u];
                int cu = eu >> 1;
                if (ku < key || (ku == key && cu < cnd)) ++r;
            }
        }
        if (r < KK) {
            int eo = (mycls == 0 ? 0 : NE_HALF) + blk * KK + r;
            out[O_EDGES + eo]      = (float)blk;            // src
            out[O_EDGES + NE + eo] = (float)(b * LL + cnd); // dst
        }
    }
}

extern "C" void kernel_launch(void* const* d_in, const int* in_sizes, int n_in,
                              void* d_out, int out_size, void* d_ws, size_t ws_size,
                              hipStream_t stream) {
    const float* pos  = (const float*)d_in[0];   // pos_heavyatom [8,256,15,3] f32
    const int*   frag = (const int*)d_in[6];     // fragment_type [8,256] i32
    const float* emb  = (const float*)d_in[7];   // edge_emb [2,16] f32
    float* out = (float*)d_out;
    float* Dm  = (float*)d_ws;                   // [8,256,256] f32 = 2 MB

    dist_kernel<<<dim3(BB * NTILE), dim3(256), 0, stream>>>(pos, Dm);
    select_kernel<<<dim3(BB * LL), dim3(256), 0, stream>>>(pos, Dm, frag,
                                                           emb, out);
}